// Round 18
// baseline (6075.876 us; speedup 1.0000x reference)
//
#include <hip/hip_runtime.h>
#include <hip/hip_bf16.h>
#include <cstdint>
#include <cstdio>

// Problem constants
#define B_   64
#define U_   512
#define D_   512
#define H_   640
#define P_   512
#define G4H  2560   // 4*H
#define NWG  40     // WGs in fallback recurrent path
#define NGRP 4      // independent batch groups (16 batches each)
#define GWG  40     // WGs per group (each owns 64 reordered gate cols)
#define HLP  650    // LDS h row stride (bf16): 325 dwords, 325%32=5 -> <=2-way banks

typedef __bf16 bf16x8 __attribute__((ext_vector_type(8)));
typedef __bf16 bf16x4 __attribute__((ext_vector_type(4)));
typedef float  f32x4  __attribute__((ext_vector_type(4)));
typedef int    i32x4  __attribute__((ext_vector_type(4)));
typedef unsigned u32x2 __attribute__((ext_vector_type(2)));

__device__ __forceinline__ float sigm(float x)     { return 1.f / (1.f + __expf(-x)); }
__device__ __forceinline__ float tanhfast(float x) { return 1.f - 2.f / (1.f + __expf(2.f * x)); }

// IC-direct (bypass L1 + per-XCD L2) ops — explicit sc0 sc1.
__device__ __forceinline__ void sysflag_store(unsigned* p, unsigned v) {
    asm volatile("global_store_dword %0, %1, off sc0 sc1" :: "v"(p), "v"(v) : "memory");
}
__device__ __forceinline__ i32x4 icload_b128(const void* p) {
    i32x4 r;
    asm volatile("global_load_dwordx4 %0, %1, off sc0 sc1"
                 : "=v"(r) : "v"(p) : "memory");
    return r;
}

// ---------------------------------------------------------------------------
// Tiled weight transpose: W[K][N] f32 -> WT[N'][K] bf16, 64x64 LDS tiles.
__global__ __launch_bounds__(256) void wconv_tiled(
    const float* __restrict__ W, __bf16* __restrict__ WT, int K, int N, int reorder) {
    __shared__ __bf16 tl[64 * 65];
    const int t  = threadIdx.x;
    const int n0 = blockIdx.x * 64, k0 = blockIdx.y * 64;
    const int cr = t & 63, rr4 = t >> 6;
    #pragma unroll
    for (int i = 0; i < 16; ++i) {
        int rl = i * 4 + rr4;
        tl[cr * 65 + rl] = (__bf16)W[(size_t)(k0 + rl) * N + n0 + cr];
    }
    __syncthreads();
    #pragma unroll
    for (int i = 0; i < 16; ++i) {
        int nl = i * 4 + rr4;
        int n  = n0 + nl;
        int np = reorder ? (4 * (n % 640) + (n / 640)) : n;
        WT[(size_t)np * K + k0 + cr] = tl[nl * 65 + cr];
    }
}

__global__ __launch_bounds__(256) void breorder_kernel(
    const float* __restrict__ b, float* __restrict__ br) {
    int n = blockIdx.x * 256 + threadIdx.x;
    if (n < G4H) br[4 * (n % 640) + (n / 640)] = b[n];
}

__global__ __launch_bounds__(256) void gather_kernel(
    const int* __restrict__ tokens, const float* __restrict__ embed,
    __bf16* __restrict__ X) {
    int tid = blockIdx.x * 256 + threadIdx.x;
    int row = tid >> 7;
    int c4  = (tid & 127) << 2;
    int tok = tokens[row];
    float4 v = *reinterpret_cast<const float4*>(embed + (size_t)tok * D_ + c4);
    union { ushort4 u; __bf16 h[4]; } o;
    o.h[0] = (__bf16)v.x; o.h[1] = (__bf16)v.y; o.h[2] = (__bf16)v.z; o.h[3] = (__bf16)v.w;
    *reinterpret_cast<ushort4*>(X + (size_t)row * D_ + c4) = o.u;
}

// Zero tagged h buffers (fast path), dense h + c (fallback). 160 x 256 threads.
__global__ __launch_bounds__(256) void zstate_kernel(
    unsigned* __restrict__ hT0, unsigned* __restrict__ hT1,
    __bf16* __restrict__ h0, __bf16* __restrict__ h1,
    float* __restrict__ cst) {
    int tid = blockIdx.x * 256 + threadIdx.x;
    if (tid < B_ * H_) {                 // 40960 dwords each
        sysflag_store(&hT0[tid], 0u);    // tag 0, h = +0.0bf16
        sysflag_store(&hT1[tid], 0u);
        h0[tid] = (__bf16)0.f; h1[tid] = (__bf16)0.f; cst[tid] = 0.f;
    }
}

// ---------------------------------------------------------------------------
// bf16 MFMA GEMM: C[M][N] = A[M][K] @ BT[N][K]^T + bias[N]. WG tile 256x64
// (4 m-subtiles/wave -> B fragments reused 4x in registers).
// ztr=1 writes rows transposed (b*U+u -> u*B+b), for Z.
__global__ __launch_bounds__(256) void gemm_kernel(
    const __bf16* __restrict__ A, const __bf16* __restrict__ BT,
    const float* __restrict__ bias,
    float* __restrict__ Cf, __bf16* __restrict__ Cb,
    int M, int N, int K, int ztr) {
    const int wv = threadIdx.x >> 6, l = threadIdx.x & 63;
    const int lr = l & 15, lh = l >> 4;
    const int m0 = blockIdx.y * 256 + wv * 16;
    const int n0 = blockIdx.x * 64;

    f32x4 acc[4][4];
    #pragma unroll
    for (int mt = 0; mt < 4; ++mt)
        #pragma unroll
        for (int nt = 0; nt < 4; ++nt) acc[mt][nt] = (f32x4){0.f, 0.f, 0.f, 0.f};

    const __bf16* Ap[4];
    #pragma unroll
    for (int mt = 0; mt < 4; ++mt)
        Ap[mt] = A + (size_t)(m0 + mt * 64 + lr) * K + lh * 8;
    const __bf16* Bp = BT + (size_t)(n0 + lr) * K + lh * 8;

    for (int k0 = 0; k0 < K; k0 += 32) {
        bf16x8 af[4];
        #pragma unroll
        for (int mt = 0; mt < 4; ++mt)
            af[mt] = *reinterpret_cast<const bf16x8*>(Ap[mt] + k0);
        #pragma unroll
        for (int nt = 0; nt < 4; ++nt) {
            bf16x8 bfv = *reinterpret_cast<const bf16x8*>(Bp + (size_t)nt * 16 * K + k0);
            #pragma unroll
            for (int mt = 0; mt < 4; ++mt)
                acc[mt][nt] = __builtin_amdgcn_mfma_f32_16x16x32_bf16(af[mt], bfv, acc[mt][nt], 0, 0, 0);
        }
    }
    #pragma unroll
    for (int mt = 0; mt < 4; ++mt) {
        #pragma unroll
        for (int nt = 0; nt < 4; ++nt) {
            int col = n0 + nt * 16 + lr;
            float bs = bias ? bias[col] : 0.f;
            #pragma unroll
            for (int r = 0; r < 4; ++r) {
                int row = m0 + mt * 64 + lh * 4 + r;
                int crow = ztr ? ((row & (U_ - 1)) * B_ + (row >> 9)) : row;
                float v = acc[mt][nt][r] + bs;
                if (Cf) Cf[(size_t)crow * N + col] = v;
                else    Cb[(size_t)crow * N + col] = (__bf16)v;
            }
        }
    }
}

// ---------------------------------------------------------------------------
// Persistent LSTM kernel (cooperative, 160 WGs). Batch-grouped + TAGGED h
// exchange ((tag<<16)|bf16 dwords, sc0 sc1): no barrier, no flags, no store
// drain — consumers poll the data itself. Deadlock-free by ping-pong
// transitivity; retry cap makes logic errors fail-visible. R18: HLP=650
// (bank-conflict-free MFMA reads), zq hoisted before the poll.
__global__ __launch_bounds__(256, 1) void lstm_seq_kernel(
    const __bf16* __restrict__ Z,       // [U][B][G4H] bf16 (pre-transposed)
    const __bf16* __restrict__ WhT,     // [G4H][H_] reordered rows
    unsigned* hT0, unsigned* hT1,       // [B_][H_] tagged dwords ping-pong
    __bf16* __restrict__ Hout,          // [B_][U_][H_]
    const int* __restrict__ plen) {
    __shared__ __bf16 hl[16 * HLP];     // 20,800 B (tag-stripped h tile)
    __shared__ float  zl[16 * 65];      //  4,160 B
    __shared__ int    wflags[4];
    const int w = blockIdx.x, tid = threadIdx.x;
    const int g = w / GWG, wl = w % GWG;
    const int wv = tid >> 6, l = tid & 63;
    const int lr = l & 15, lh = l >> 4;

    // Wh slice -> registers (one-time, cached). 20 k-tiles of bf16x8 per lane.
    bf16x8 wreg[20];
    {
        const __bf16* Bp = WhT + (size_t)(wl * 64 + wv * 16 + lr) * H_ + lh * 8;
        #pragma unroll
        for (int kk = 0; kk < 20; ++kk)
            wreg[kk] = *reinterpret_cast<const bf16x8*>(Bp + kk * 32);
    }

    // Gate phase: thread owns (batch bb, hidden j = wl*16+jj)
    const int bb = tid >> 4, jj = tid & 15;
    const int bg = g * 16 + bb;
    const int pl = plen[bg];
    float c_r = 0.f, h_r = 0.f;

    for (unsigned t = 0; t < U_; ++t) {
        const unsigned* hTin = (t & 1u) ? hT1 : hT0;
        unsigned*      hTout = (t & 1u) ? hT0 : hT1;

        // Z quad (cached) — issued before the poll; drained by poll's vmcnt(0)
        bf16x4 zq = *reinterpret_cast<const bf16x4*>(
            Z + ((size_t)t * B_ + bg) * G4H + wl * 64 + 4 * jj);

        // ---- tag-poll load: retry until all 40 dwords/thread carry tag >= t
        i32x4 ld[10];
        int spin = 0;
        for (;;) {
            #pragma unroll
            for (int i = 0; i < 10; ++i) {
                int c = tid + i * 256;
                int row = c / 160, dcol = (c % 160) * 4;
                ld[i] = icload_b128(hTin + (size_t)(g * 16 + row) * H_ + dcol);
            }
            asm volatile("s_waitcnt vmcnt(0)" ::: "memory");
            __builtin_amdgcn_sched_barrier(0);
            bool ok = true;
            #pragma unroll
            for (int i = 0; i < 10; ++i)
                #pragma unroll
                for (int e = 0; e < 4; ++e)
                    ok &= (((unsigned)ld[i][e]) >> 16) >= t;
            bool wok = (__ballot(ok) == ~0ull);
            if (l == 0) wflags[wv] = wok ? 1 : 0;
            __syncthreads();   // also separates prior-step LDS reads from writes below
            bool all4 = wflags[0] && wflags[1] && wflags[2] && wflags[3];
            if (all4 || ++spin > 100000) break;
            __syncthreads();
        }

        // ---- strip tags -> LDS h tile
        #pragma unroll
        for (int i = 0; i < 10; ++i) {
            int c = tid + i * 256;
            int row = c / 160, dcol = (c % 160) * 4;
            u32x2 pk2;
            pk2[0] = ((unsigned)ld[i][0] & 0xFFFFu) | ((unsigned)ld[i][1] << 16);
            pk2[1] = ((unsigned)ld[i][2] & 0xFFFFu) | ((unsigned)ld[i][3] << 16);
            *reinterpret_cast<u32x2*>(hl + (size_t)row * HLP + dcol) = pk2;
        }
        __syncthreads();

        // ---- h @ Wh : A from LDS, B from registers
        f32x4 acc = (f32x4){0.f, 0.f, 0.f, 0.f};
        const __bf16* Al = hl + (size_t)lr * HLP + lh * 8;
        #pragma unroll
        for (int kk = 0; kk < 20; ++kk) {
            bf16x8 af = *reinterpret_cast<const bf16x8*>(Al + kk * 32);
            acc = __builtin_amdgcn_mfma_f32_16x16x32_bf16(af, wreg[kk], acc, 0, 0, 0);
        }
        // redistribute through LDS (MFMA layout -> gate layout)
        #pragma unroll
        for (int r = 0; r < 4; ++r)
            zl[(lh * 4 + r) * 65 + wv * 16 + lr] = acc[r];
        __syncthreads();

        // ---- gates + masked state update; tagged store (fire-and-forget)
        {
            const float* zp = &zl[bb * 65 + 4 * jj];
            float zi = zp[0] + (float)zq[0];
            float zf = zp[1] + (float)zq[1];
            float zg = zp[2] + (float)zq[2];
            float zo = zp[3] + (float)zq[3];
            float ig = sigm(zi), fg = sigm(zf), og = sigm(zo);
            float gg = tanhfast(zg);
            float cnew = fg * c_r + ig * gg;
            float hnew = og * tanhfast(cnew);
            bool m = (int)t < pl;
            c_r = m ? cnew : c_r;
            h_r = m ? hnew : h_r;
            union { __bf16 h; unsigned short u; } pk; pk.h = (__bf16)h_r;
            unsigned tag = ((t + 1u) << 16) | (unsigned)pk.u;
            sysflag_store(hTout + (size_t)bg * H_ + wl * 16 + jj, tag);
            Hout[((size_t)bg * U_ + t) * H_ + wl * 16 + jj] = pk.h;
        }
    }
}

// ---------------------------------------------------------------------------
// Fallback: one launch per timestep (inter-dispatch coherence). Dense h.
__global__ __launch_bounds__(256) void lstm_step_fb(
    const __bf16* __restrict__ Z, const __bf16* __restrict__ WhT,
    const __bf16* __restrict__ hin, __bf16* __restrict__ hout,
    float* __restrict__ cst, __bf16* __restrict__ Hout,
    const int* __restrict__ plen, int t) {
    __shared__ float zl[64 * 65];
    const int w = blockIdx.x, tid = threadIdx.x;
    const int wv = tid >> 6, l = tid & 63;
    const int lr = l & 15, lh = l >> 4;

    f32x4 acc[4];
    #pragma unroll
    for (int mt = 0; mt < 4; ++mt) acc[mt] = (f32x4){0.f, 0.f, 0.f, 0.f};
    const __bf16* Bp = WhT + (size_t)(w * 64 + wv * 16 + lr) * H_ + lh * 8;
    const __bf16* Ap = hin + (size_t)lr * H_ + lh * 8;
    for (int kk = 0; kk < 20; ++kk) {
        bf16x8 bfv = *reinterpret_cast<const bf16x8*>(Bp + kk * 32);
        #pragma unroll
        for (int mt = 0; mt < 4; ++mt) {
            bf16x8 af = *reinterpret_cast<const bf16x8*>(Ap + (size_t)mt * 16 * H_ + kk * 32);
            acc[mt] = __builtin_amdgcn_mfma_f32_16x16x32_bf16(af, bfv, acc[mt], 0, 0, 0);
        }
    }
    {
        int cl = wv * 16 + lr;
        #pragma unroll
        for (int mt = 0; mt < 4; ++mt)
            #pragma unroll
            for (int r = 0; r < 4; ++r)
                zl[(mt * 16 + lh * 4 + r) * 65 + cl] = acc[mt][r];
    }
    __syncthreads();

    const int bb0 = tid >> 3, jp = tid & 7;
    #pragma unroll
    for (int it = 0; it < 2; ++it) {
        const int bb = (it ? bb0 + 32 : bb0);
        const int pl = plen[bb];
        const bf16x8 zq = *reinterpret_cast<const bf16x8*>(
            Z + ((size_t)t * B_ + bb) * G4H + w * 64 + 8 * jp);
        const float* zp = &zl[bb * 65 + 8 * jp];
        const size_t co = (size_t)w * 16 + 2 * jp;
        union { __bf16 h[2]; unsigned u; } ho_, hi_;
        hi_.u = *reinterpret_cast<const unsigned*>(hin + (size_t)bb * H_ + co);
        #pragma unroll
        for (int e = 0; e < 2; ++e) {
            size_t sidx = (size_t)bb * H_ + co + e;
            float zi = zp[4 * e + 0] + (float)zq[4 * e + 0];
            float zf = zp[4 * e + 1] + (float)zq[4 * e + 1];
            float zg = zp[4 * e + 2] + (float)zq[4 * e + 2];
            float zo = zp[4 * e + 3] + (float)zq[4 * e + 3];
            float ig = sigm(zi), fg = sigm(zf), og = sigm(zo);
            float gg = tanhfast(zg);
            float cold = cst[sidx];
            float cnew = fg * cold + ig * gg;
            float hnew = og * tanhfast(cnew);
            bool m = t < pl;
            cst[sidx] = m ? cnew : cold;
            ho_.h[e] = m ? (__bf16)hnew : hi_.h[e];
        }
        *reinterpret_cast<unsigned*>(hout + (size_t)bb * H_ + co) = ho_.u;
        *reinterpret_cast<unsigned*>(Hout + ((size_t)bb * U_ + t) * H_ + co) = ho_.u;
    }
}

// ---------------------------------------------------------------------------
__global__ __launch_bounds__(256) void ln_kernel(
    __bf16* __restrict__ X, const float* __restrict__ gamma, const float* __restrict__ beta) {
    __shared__ float s1[256];
    __shared__ float s2[256];
    const int tid = threadIdx.x;
    __bf16* xp = X + (size_t)blockIdx.x * H_;
    float xv[3] = {0.f, 0.f, 0.f};
    float a = 0.f, b = 0.f;
    #pragma unroll
    for (int i = 0; i < 3; ++i) {
        int j = tid + 256 * i;
        if (j < H_) { float v = (float)xp[j]; xv[i] = v; a += v; b += v * v; }
    }
    s1[tid] = a; s2[tid] = b;
    __syncthreads();
    for (int st = 128; st > 0; st >>= 1) {
        if (tid < st) { s1[tid] += s1[tid + st]; s2[tid] += s2[tid + st]; }
        __syncthreads();
    }
    float mean = s1[0] * (1.f / H_);
    float var  = s2[0] * (1.f / H_) - mean * mean;
    float inv  = rsqrtf(var + 0.001f);
    #pragma unroll
    for (int i = 0; i < 3; ++i) {
        int j = tid + 256 * i;
        if (j < H_) xp[j] = (__bf16)((xv[i] - mean) * inv * gamma[j] + beta[j]);
    }
}

// ---------------------------------------------------------------------------
extern "C" void kernel_launch(void* const* d_in, const int* in_sizes, int n_in,
                              void* d_out, int out_size, void* d_ws, size_t ws_size,
                              hipStream_t stream) {
    (void)in_sizes; (void)n_in; (void)out_size;
    const int*   tokens = (const int*)d_in[0];
    const int*   plen   = (const int*)d_in[1];
    const float* embed  = (const float*)d_in[2];
    const float* W0x = (const float*)d_in[3];
    const float* W0h = (const float*)d_in[4];
    const float* b0  = (const float*)d_in[5];
    const float* g0  = (const float*)d_in[6];
    const float* be0 = (const float*)d_in[7];
    const float* P0w = (const float*)d_in[8];
    const float* P0b = (const float*)d_in[9];
    const float* W1x = (const float*)d_in[10];
    const float* W1h = (const float*)d_in[11];
    const float* b1  = (const float*)d_in[12];
    const float* g1  = (const float*)d_in[13];
    const float* be1 = (const float*)d_in[14];
    const float* P1w = (const float*)d_in[15];
    const float* P1b = (const float*)d_in[16];
    float* out = (float*)d_out;

    char* p = (char*)d_ws;
    size_t used = 0;
    auto take = [&](size_t bytes) {
        char* r = p; size_t pad = (bytes + 255) & ~(size_t)255;
        p += pad; used += pad; return r;
    };
    __bf16* WT0x_ = (__bf16*)take((size_t)G4H * D_ * 2);
    __bf16* WT0h_ = (__bf16*)take((size_t)G4H * H_ * 2);
    __bf16* WT1x_ = (__bf16*)take((size_t)G4H * P_ * 2);
    __bf16* WT1h_ = (__bf16*)take((size_t)G4H * H_ * 2);
    __bf16* PT0w_ = (__bf16*)take((size_t)P_ * H_ * 2);
    __bf16* PT1w_ = (__bf16*)take((size_t)P_ * H_ * 2);
    float*  b0r   = (float*)take(G4H * 4);
    float*  b1r   = (float*)take(G4H * 4);
    unsigned* hT0 = (unsigned*)take((size_t)B_ * H_ * 4);   // tagged ping
    unsigned* hT1 = (unsigned*)take((size_t)B_ * H_ * 4);   // tagged pong
    __bf16* hb0   = (__bf16*)take((size_t)B_ * H_ * 2);     // fallback dense
    __bf16* hb1   = (__bf16*)take((size_t)B_ * H_ * 2);
    float*  cst   = (float*)take((size_t)B_ * H_ * 4);
    __bf16* Hbuf  = (__bf16*)take((size_t)B_ * U_ * H_ * 2);
    __bf16* Z     = (__bf16*)take((size_t)B_ * U_ * G4H * 2);  // [U][B][4H]

    if (used > ws_size) {
        fprintf(stderr, "kernel_launch: ws_size too small (%zu < %zu)\n",
                ws_size, used);
        return;
    }
    // Xbf aliases d_out (67 MB f32): dead before the final GEMM overwrites d_out.
    __bf16* Xbf = (__bf16*)d_out;

    dim3 blk(256);
    // Tiled weight transposes (all dims multiples of 64)
    wconv_tiled<<<dim3(G4H / 64, D_ / 64), blk, 0, stream>>>(W0x, WT0x_, D_, G4H, 1);
    wconv_tiled<<<dim3(G4H / 64, H_ / 64), blk, 0, stream>>>(W0h, WT0h_, H_, G4H, 1);
    wconv_tiled<<<dim3(G4H / 64, P_ / 64), blk, 0, stream>>>(W1x, WT1x_, P_, G4H, 1);
    wconv_tiled<<<dim3(G4H / 64, H_ / 64), blk, 0, stream>>>(W1h, WT1h_, H_, G4H, 1);
    wconv_tiled<<<dim3(P_ / 64, H_ / 64), blk, 0, stream>>>(P0w, PT0w_, H_, P_, 0);
    wconv_tiled<<<dim3(P_ / 64, H_ / 64), blk, 0, stream>>>(P1w, PT1w_, H_, P_, 0);
    breorder_kernel<<<10, blk, 0, stream>>>(b0, b0r);
    breorder_kernel<<<10, blk, 0, stream>>>(b1, b1r);
    gather_kernel<<<(B_ * U_ * D_ / 4 + 255) / 256, blk, 0, stream>>>(tokens, embed, Xbf);

    // Recurrent layer driver: cooperative persistent kernel; on launch error,
    // print diagnostics and fall back to 512 per-step launches.
    auto run_lstm = [&](const __bf16* Zc, const __bf16* Wc) {
        zstate_kernel<<<160, blk, 0, stream>>>(hT0, hT1, hb0, hb1, cst);
        unsigned* t0 = hT0; unsigned* t1 = hT1; __bf16* Ha = Hbuf;
        const int* pl = plen;
        void* args[] = { (void*)&Zc, (void*)&Wc, (void*)&t0, (void*)&t1,
                         (void*)&Ha, (void*)&pl };
        hipError_t ce = hipLaunchCooperativeKernel((void*)lstm_seq_kernel,
                                                   dim3(NGRP * GWG), dim3(256),
                                                   args, 0, stream);
        if (ce != hipSuccess) {
            fprintf(stderr, "[lstm] coop launch failed: %d (%s) — per-step fallback\n",
                    (int)ce, hipGetErrorName(ce));
            for (int t = 0; t < U_; ++t) {
                const __bf16* hi = (t & 1) ? hb1 : hb0;
                __bf16*       ho = (t & 1) ? hb0 : hb1;
                lstm_step_fb<<<NWG, blk, 0, stream>>>(Zc, Wc, hi, ho, cst, Hbuf, plen, t);
            }
        }
    };

    // ---- layer 0 ----
    gemm_kernel<<<dim3(G4H / 64, B_ * U_ / 256), blk, 0, stream>>>(
        Xbf, WT0x_, b0r, nullptr, Z, B_ * U_, G4H, D_, 1);
    run_lstm(Z, WT0h_);
    ln_kernel<<<B_ * U_, blk, 0, stream>>>(Hbuf, g0, be0);
    gemm_kernel<<<dim3(P_ / 64, B_ * U_ / 256), blk, 0, stream>>>(
        Hbuf, PT0w_, P0b, nullptr, Xbf, B_ * U_, P_, H_, 0);

    // ---- layer 1 ----
    gemm_kernel<<<dim3(G4H / 64, B_ * U_ / 256), blk, 0, stream>>>(
        Xbf, WT1x_, b1r, nullptr, Z, B_ * U_, G4H, P_, 1);
    run_lstm(Z, WT1h_);
    ln_kernel<<<B_ * U_, blk, 0, stream>>>(Hbuf, g1, be1);
    gemm_kernel<<<dim3(P_ / 64, B_ * U_ / 256), blk, 0, stream>>>(
        Hbuf, PT1w_, P1b, out, nullptr, B_ * U_, P_, H_, 0);
}

// Round 19
// 6048.238 us; speedup vs baseline: 1.0046x; 1.0046x over previous
//
#include <hip/hip_runtime.h>
#include <hip/hip_bf16.h>
#include <cstdint>
#include <cstdio>

// Problem constants
#define B_   64
#define U_   512
#define D_   512
#define H_   640
#define P_   512
#define G4H  2560   // 4*H
#define NWG  40     // WGs in fallback recurrent path
#define NGRP 4      // independent batch groups (16 batches each)
#define GWG  40     // WGs per group (each owns 64 reordered gate cols)
#define HLP  650    // LDS h row stride (bf16): 325 dwords, 325%32=5 -> <=2-way banks

typedef __bf16 bf16x8 __attribute__((ext_vector_type(8)));
typedef __bf16 bf16x4 __attribute__((ext_vector_type(4)));
typedef float  f32x4  __attribute__((ext_vector_type(4)));
typedef int    i32x4  __attribute__((ext_vector_type(4)));
typedef unsigned u32x2 __attribute__((ext_vector_type(2)));

__device__ __forceinline__ float sigm(float x)     { return 1.f / (1.f + __expf(-x)); }
__device__ __forceinline__ float tanhfast(float x) { return 1.f - 2.f / (1.f + __expf(2.f * x)); }

// IC-direct (bypass L1 + per-XCD L2) ops — explicit sc0 sc1.
__device__ __forceinline__ void sysflag_store(unsigned* p, unsigned v) {
    asm volatile("global_store_dword %0, %1, off sc0 sc1" :: "v"(p), "v"(v) : "memory");
}
__device__ __forceinline__ i32x4 icload_b128(const void* p) {
    i32x4 r;
    asm volatile("global_load_dwordx4 %0, %1, off sc0 sc1"
                 : "=v"(r) : "v"(p) : "memory");
    return r;
}

// ---------------------------------------------------------------------------
// Tiled weight transpose: W[K][N] f32 -> WT[N'][K] bf16, 64x64 LDS tiles.
__global__ __launch_bounds__(256) void wconv_tiled(
    const float* __restrict__ W, __bf16* __restrict__ WT, int K, int N, int reorder) {
    __shared__ __bf16 tl[64 * 65];
    const int t  = threadIdx.x;
    const int n0 = blockIdx.x * 64, k0 = blockIdx.y * 64;
    const int cr = t & 63, rr4 = t >> 6;
    #pragma unroll
    for (int i = 0; i < 16; ++i) {
        int rl = i * 4 + rr4;
        tl[cr * 65 + rl] = (__bf16)W[(size_t)(k0 + rl) * N + n0 + cr];
    }
    __syncthreads();
    #pragma unroll
    for (int i = 0; i < 16; ++i) {
        int nl = i * 4 + rr4;
        int n  = n0 + nl;
        int np = reorder ? (4 * (n % 640) + (n / 640)) : n;
        WT[(size_t)np * K + k0 + cr] = tl[nl * 65 + cr];
    }
}

__global__ __launch_bounds__(256) void breorder_kernel(
    const float* __restrict__ b, float* __restrict__ br) {
    int n = blockIdx.x * 256 + threadIdx.x;
    if (n < G4H) br[4 * (n % 640) + (n / 640)] = b[n];
}

__global__ __launch_bounds__(256) void gather_kernel(
    const int* __restrict__ tokens, const float* __restrict__ embed,
    __bf16* __restrict__ X) {
    int tid = blockIdx.x * 256 + threadIdx.x;
    int row = tid >> 7;
    int c4  = (tid & 127) << 2;
    int tok = tokens[row];
    float4 v = *reinterpret_cast<const float4*>(embed + (size_t)tok * D_ + c4);
    union { ushort4 u; __bf16 h[4]; } o;
    o.h[0] = (__bf16)v.x; o.h[1] = (__bf16)v.y; o.h[2] = (__bf16)v.z; o.h[3] = (__bf16)v.w;
    *reinterpret_cast<ushort4*>(X + (size_t)row * D_ + c4) = o.u;
}

// Zero tagged h buffers (fast path), dense h + c (fallback). 160 x 256 threads.
__global__ __launch_bounds__(256) void zstate_kernel(
    unsigned* __restrict__ hT0, unsigned* __restrict__ hT1,
    __bf16* __restrict__ h0, __bf16* __restrict__ h1,
    float* __restrict__ cst) {
    int tid = blockIdx.x * 256 + threadIdx.x;
    if (tid < B_ * H_) {                 // 40960 dwords each
        sysflag_store(&hT0[tid], 0u);    // tag 0, h = +0.0bf16
        sysflag_store(&hT1[tid], 0u);
        h0[tid] = (__bf16)0.f; h1[tid] = (__bf16)0.f; cst[tid] = 0.f;
    }
}

// ---------------------------------------------------------------------------
// bf16 MFMA GEMM: C[M][N] = A[M][K] @ BT[N][K]^T + bias[N]. WG tile 256x64
// (4 m-subtiles/wave -> B fragments reused 4x in registers).
// ztr=1 writes rows transposed (b*U+u -> u*B+b), for Z.
__global__ __launch_bounds__(256) void gemm_kernel(
    const __bf16* __restrict__ A, const __bf16* __restrict__ BT,
    const float* __restrict__ bias,
    float* __restrict__ Cf, __bf16* __restrict__ Cb,
    int M, int N, int K, int ztr) {
    const int wv = threadIdx.x >> 6, l = threadIdx.x & 63;
    const int lr = l & 15, lh = l >> 4;
    const int m0 = blockIdx.y * 256 + wv * 16;
    const int n0 = blockIdx.x * 64;

    f32x4 acc[4][4];
    #pragma unroll
    for (int mt = 0; mt < 4; ++mt)
        #pragma unroll
        for (int nt = 0; nt < 4; ++nt) acc[mt][nt] = (f32x4){0.f, 0.f, 0.f, 0.f};

    const __bf16* Ap[4];
    #pragma unroll
    for (int mt = 0; mt < 4; ++mt)
        Ap[mt] = A + (size_t)(m0 + mt * 64 + lr) * K + lh * 8;
    const __bf16* Bp = BT + (size_t)(n0 + lr) * K + lh * 8;

    for (int k0 = 0; k0 < K; k0 += 32) {
        bf16x8 af[4];
        #pragma unroll
        for (int mt = 0; mt < 4; ++mt)
            af[mt] = *reinterpret_cast<const bf16x8*>(Ap[mt] + k0);
        #pragma unroll
        for (int nt = 0; nt < 4; ++nt) {
            bf16x8 bfv = *reinterpret_cast<const bf16x8*>(Bp + (size_t)nt * 16 * K + k0);
            #pragma unroll
            for (int mt = 0; mt < 4; ++mt)
                acc[mt][nt] = __builtin_amdgcn_mfma_f32_16x16x32_bf16(af[mt], bfv, acc[mt][nt], 0, 0, 0);
        }
    }
    #pragma unroll
    for (int mt = 0; mt < 4; ++mt) {
        #pragma unroll
        for (int nt = 0; nt < 4; ++nt) {
            int col = n0 + nt * 16 + lr;
            float bs = bias ? bias[col] : 0.f;
            #pragma unroll
            for (int r = 0; r < 4; ++r) {
                int row = m0 + mt * 64 + lh * 4 + r;
                int crow = ztr ? ((row & (U_ - 1)) * B_ + (row >> 9)) : row;
                float v = acc[mt][nt][r] + bs;
                if (Cf) Cf[(size_t)crow * N + col] = v;
                else    Cb[(size_t)crow * N + col] = (__bf16)v;
            }
        }
    }
}

// ---------------------------------------------------------------------------
// Persistent LSTM kernel (cooperative, 160 WGs). Batch-grouped + TAGGED h
// exchange ((tag<<16)|bf16 dwords, sc0 sc1): no barrier, no flags, no store
// drain — consumers poll the data itself. Deadlock-free by ping-pong
// transitivity; retry cap makes logic errors fail-visible.
// R19 = R17 structure + HLP=650 (conflict-free MFMA reads). zq load stays in
// R17's slot (after tag-strip): its HBM latency hides under LDS+sync+MFMA,
// NOT on the poll path (R18's hoist cost ~1 extra retry/step).
__global__ __launch_bounds__(256, 1) void lstm_seq_kernel(
    const __bf16* __restrict__ Z,       // [U][B][G4H] bf16 (pre-transposed)
    const __bf16* __restrict__ WhT,     // [G4H][H_] reordered rows
    unsigned* hT0, unsigned* hT1,       // [B_][H_] tagged dwords ping-pong
    __bf16* __restrict__ Hout,          // [B_][U_][H_]
    const int* __restrict__ plen) {
    __shared__ __bf16 hl[16 * HLP];     // 20,800 B (tag-stripped h tile)
    __shared__ float  zl[16 * 65];      //  4,160 B
    __shared__ int    wflags[4];
    const int w = blockIdx.x, tid = threadIdx.x;
    const int g = w / GWG, wl = w % GWG;
    const int wv = tid >> 6, l = tid & 63;
    const int lr = l & 15, lh = l >> 4;

    // Wh slice -> registers (one-time, cached). 20 k-tiles of bf16x8 per lane.
    bf16x8 wreg[20];
    {
        const __bf16* Bp = WhT + (size_t)(wl * 64 + wv * 16 + lr) * H_ + lh * 8;
        #pragma unroll
        for (int kk = 0; kk < 20; ++kk)
            wreg[kk] = *reinterpret_cast<const bf16x8*>(Bp + kk * 32);
    }

    // Gate phase: thread owns (batch bb, hidden j = wl*16+jj)
    const int bb = tid >> 4, jj = tid & 15;
    const int bg = g * 16 + bb;
    const int pl = plen[bg];
    float c_r = 0.f, h_r = 0.f;

    for (unsigned t = 0; t < U_; ++t) {
        const unsigned* hTin = (t & 1u) ? hT1 : hT0;
        unsigned*      hTout = (t & 1u) ? hT0 : hT1;

        // ---- tag-poll load: retry until all 40 dwords/thread carry tag >= t
        i32x4 ld[10];
        int spin = 0;
        for (;;) {
            #pragma unroll
            for (int i = 0; i < 10; ++i) {
                int c = tid + i * 256;
                int row = c / 160, dcol = (c % 160) * 4;
                ld[i] = icload_b128(hTin + (size_t)(g * 16 + row) * H_ + dcol);
            }
            asm volatile("s_waitcnt vmcnt(0)" ::: "memory");
            __builtin_amdgcn_sched_barrier(0);
            bool ok = true;
            #pragma unroll
            for (int i = 0; i < 10; ++i)
                #pragma unroll
                for (int e = 0; e < 4; ++e)
                    ok &= (((unsigned)ld[i][e]) >> 16) >= t;
            bool wok = (__ballot(ok) == ~0ull);
            if (l == 0) wflags[wv] = wok ? 1 : 0;
            __syncthreads();   // also separates prior-step LDS reads from writes below
            bool all4 = wflags[0] && wflags[1] && wflags[2] && wflags[3];
            if (all4 || ++spin > 100000) break;
            __syncthreads();
        }

        // ---- strip tags -> LDS h tile
        #pragma unroll
        for (int i = 0; i < 10; ++i) {
            int c = tid + i * 256;
            int row = c / 160, dcol = (c % 160) * 4;
            u32x2 pk2;
            pk2[0] = ((unsigned)ld[i][0] & 0xFFFFu) | ((unsigned)ld[i][1] << 16);
            pk2[1] = ((unsigned)ld[i][2] & 0xFFFFu) | ((unsigned)ld[i][3] << 16);
            *reinterpret_cast<u32x2*>(hl + (size_t)row * HLP + dcol) = pk2;
        }
        // Z quad (cached) — issued here, consumed after sync; latency overlaps
        bf16x4 zq = *reinterpret_cast<const bf16x4*>(
            Z + ((size_t)t * B_ + bg) * G4H + wl * 64 + 4 * jj);
        __syncthreads();

        // ---- h @ Wh : A from LDS, B from registers
        f32x4 acc = (f32x4){0.f, 0.f, 0.f, 0.f};
        const __bf16* Al = hl + (size_t)lr * HLP + lh * 8;
        #pragma unroll
        for (int kk = 0; kk < 20; ++kk) {
            bf16x8 af = *reinterpret_cast<const bf16x8*>(Al + kk * 32);
            acc = __builtin_amdgcn_mfma_f32_16x16x32_bf16(af, wreg[kk], acc, 0, 0, 0);
        }
        // redistribute through LDS (MFMA layout -> gate layout)
        #pragma unroll
        for (int r = 0; r < 4; ++r)
            zl[(lh * 4 + r) * 65 + wv * 16 + lr] = acc[r];
        __syncthreads();

        // ---- gates + masked state update; tagged store (fire-and-forget)
        {
            const float* zp = &zl[bb * 65 + 4 * jj];
            float zi = zp[0] + (float)zq[0];
            float zf = zp[1] + (float)zq[1];
            float zg = zp[2] + (float)zq[2];
            float zo = zp[3] + (float)zq[3];
            float ig = sigm(zi), fg = sigm(zf), og = sigm(zo);
            float gg = tanhfast(zg);
            float cnew = fg * c_r + ig * gg;
            float hnew = og * tanhfast(cnew);
            bool m = (int)t < pl;
            c_r = m ? cnew : c_r;
            h_r = m ? hnew : h_r;
            union { __bf16 h; unsigned short u; } pk; pk.h = (__bf16)h_r;
            unsigned tag = ((t + 1u) << 16) | (unsigned)pk.u;
            sysflag_store(hTout + (size_t)bg * H_ + wl * 16 + jj, tag);
            Hout[((size_t)bg * U_ + t) * H_ + wl * 16 + jj] = pk.h;
        }
    }
}

// ---------------------------------------------------------------------------
// Fallback: one launch per timestep (inter-dispatch coherence). Dense h.
__global__ __launch_bounds__(256) void lstm_step_fb(
    const __bf16* __restrict__ Z, const __bf16* __restrict__ WhT,
    const __bf16* __restrict__ hin, __bf16* __restrict__ hout,
    float* __restrict__ cst, __bf16* __restrict__ Hout,
    const int* __restrict__ plen, int t) {
    __shared__ float zl[64 * 65];
    const int w = blockIdx.x, tid = threadIdx.x;
    const int wv = tid >> 6, l = tid & 63;
    const int lr = l & 15, lh = l >> 4;

    f32x4 acc[4];
    #pragma unroll
    for (int mt = 0; mt < 4; ++mt) acc[mt] = (f32x4){0.f, 0.f, 0.f, 0.f};
    const __bf16* Bp = WhT + (size_t)(w * 64 + wv * 16 + lr) * H_ + lh * 8;
    const __bf16* Ap = hin + (size_t)lr * H_ + lh * 8;
    for (int kk = 0; kk < 20; ++kk) {
        bf16x8 bfv = *reinterpret_cast<const bf16x8*>(Bp + kk * 32);
        #pragma unroll
        for (int mt = 0; mt < 4; ++mt) {
            bf16x8 af = *reinterpret_cast<const bf16x8*>(Ap + (size_t)mt * 16 * H_ + kk * 32);
            acc[mt] = __builtin_amdgcn_mfma_f32_16x16x32_bf16(af, bfv, acc[mt], 0, 0, 0);
        }
    }
    {
        int cl = wv * 16 + lr;
        #pragma unroll
        for (int mt = 0; mt < 4; ++mt)
            #pragma unroll
            for (int r = 0; r < 4; ++r)
                zl[(mt * 16 + lh * 4 + r) * 65 + cl] = acc[mt][r];
    }
    __syncthreads();

    const int bb0 = tid >> 3, jp = tid & 7;
    #pragma unroll
    for (int it = 0; it < 2; ++it) {
        const int bb = (it ? bb0 + 32 : bb0);
        const int pl = plen[bb];
        const bf16x8 zq = *reinterpret_cast<const bf16x8*>(
            Z + ((size_t)t * B_ + bb) * G4H + w * 64 + 8 * jp);
        const float* zp = &zl[bb * 65 + 8 * jp];
        const size_t co = (size_t)w * 16 + 2 * jp;
        union { __bf16 h[2]; unsigned u; } ho_, hi_;
        hi_.u = *reinterpret_cast<const unsigned*>(hin + (size_t)bb * H_ + co);
        #pragma unroll
        for (int e = 0; e < 2; ++e) {
            size_t sidx = (size_t)bb * H_ + co + e;
            float zi = zp[4 * e + 0] + (float)zq[4 * e + 0];
            float zf = zp[4 * e + 1] + (float)zq[4 * e + 1];
            float zg = zp[4 * e + 2] + (float)zq[4 * e + 2];
            float zo = zp[4 * e + 3] + (float)zq[4 * e + 3];
            float ig = sigm(zi), fg = sigm(zf), og = sigm(zo);
            float gg = tanhfast(zg);
            float cold = cst[sidx];
            float cnew = fg * cold + ig * gg;
            float hnew = og * tanhfast(cnew);
            bool m = t < pl;
            cst[sidx] = m ? cnew : cold;
            ho_.h[e] = m ? (__bf16)hnew : hi_.h[e];
        }
        *reinterpret_cast<unsigned*>(hout + (size_t)bb * H_ + co) = ho_.u;
        *reinterpret_cast<unsigned*>(Hout + ((size_t)bb * U_ + t) * H_ + co) = ho_.u;
    }
}

// ---------------------------------------------------------------------------
__global__ __launch_bounds__(256) void ln_kernel(
    __bf16* __restrict__ X, const float* __restrict__ gamma, const float* __restrict__ beta) {
    __shared__ float s1[256];
    __shared__ float s2[256];
    const int tid = threadIdx.x;
    __bf16* xp = X + (size_t)blockIdx.x * H_;
    float xv[3] = {0.f, 0.f, 0.f};
    float a = 0.f, b = 0.f;
    #pragma unroll
    for (int i = 0; i < 3; ++i) {
        int j = tid + 256 * i;
        if (j < H_) { float v = (float)xp[j]; xv[i] = v; a += v; b += v * v; }
    }
    s1[tid] = a; s2[tid] = b;
    __syncthreads();
    for (int st = 128; st > 0; st >>= 1) {
        if (tid < st) { s1[tid] += s1[tid + st]; s2[tid] += s2[tid + st]; }
        __syncthreads();
    }
    float mean = s1[0] * (1.f / H_);
    float var  = s2[0] * (1.f / H_) - mean * mean;
    float inv  = rsqrtf(var + 0.001f);
    #pragma unroll
    for (int i = 0; i < 3; ++i) {
        int j = tid + 256 * i;
        if (j < H_) xp[j] = (__bf16)((xv[i] - mean) * inv * gamma[j] + beta[j]);
    }
}

// ---------------------------------------------------------------------------
extern "C" void kernel_launch(void* const* d_in, const int* in_sizes, int n_in,
                              void* d_out, int out_size, void* d_ws, size_t ws_size,
                              hipStream_t stream) {
    (void)in_sizes; (void)n_in; (void)out_size;
    const int*   tokens = (const int*)d_in[0];
    const int*   plen   = (const int*)d_in[1];
    const float* embed  = (const float*)d_in[2];
    const float* W0x = (const float*)d_in[3];
    const float* W0h = (const float*)d_in[4];
    const float* b0  = (const float*)d_in[5];
    const float* g0  = (const float*)d_in[6];
    const float* be0 = (const float*)d_in[7];
    const float* P0w = (const float*)d_in[8];
    const float* P0b = (const float*)d_in[9];
    const float* W1x = (const float*)d_in[10];
    const float* W1h = (const float*)d_in[11];
    const float* b1  = (const float*)d_in[12];
    const float* g1  = (const float*)d_in[13];
    const float* be1 = (const float*)d_in[14];
    const float* P1w = (const float*)d_in[15];
    const float* P1b = (const float*)d_in[16];
    float* out = (float*)d_out;

    char* p = (char*)d_ws;
    size_t used = 0;
    auto take = [&](size_t bytes) {
        char* r = p; size_t pad = (bytes + 255) & ~(size_t)255;
        p += pad; used += pad; return r;
    };
    __bf16* WT0x_ = (__bf16*)take((size_t)G4H * D_ * 2);
    __bf16* WT0h_ = (__bf16*)take((size_t)G4H * H_ * 2);
    __bf16* WT1x_ = (__bf16*)take((size_t)G4H * P_ * 2);
    __bf16* WT1h_ = (__bf16*)take((size_t)G4H * H_ * 2);
    __bf16* PT0w_ = (__bf16*)take((size_t)P_ * H_ * 2);
    __bf16* PT1w_ = (__bf16*)take((size_t)P_ * H_ * 2);
    float*  b0r   = (float*)take(G4H * 4);
    float*  b1r   = (float*)take(G4H * 4);
    unsigned* hT0 = (unsigned*)take((size_t)B_ * H_ * 4);   // tagged ping
    unsigned* hT1 = (unsigned*)take((size_t)B_ * H_ * 4);   // tagged pong
    __bf16* hb0   = (__bf16*)take((size_t)B_ * H_ * 2);     // fallback dense
    __bf16* hb1   = (__bf16*)take((size_t)B_ * H_ * 2);
    float*  cst   = (float*)take((size_t)B_ * H_ * 4);
    __bf16* Hbuf  = (__bf16*)take((size_t)B_ * U_ * H_ * 2);
    __bf16* Z     = (__bf16*)take((size_t)B_ * U_ * G4H * 2);  // [U][B][4H]

    if (used > ws_size) {
        fprintf(stderr, "kernel_launch: ws_size too small (%zu < %zu)\n",
                ws_size, used);
        return;
    }
    // Xbf aliases d_out (67 MB f32): dead before the final GEMM overwrites d_out.
    __bf16* Xbf = (__bf16*)d_out;

    dim3 blk(256);
    // Tiled weight transposes (all dims multiples of 64)
    wconv_tiled<<<dim3(G4H / 64, D_ / 64), blk, 0, stream>>>(W0x, WT0x_, D_, G4H, 1);
    wconv_tiled<<<dim3(G4H / 64, H_ / 64), blk, 0, stream>>>(W0h, WT0h_, H_, G4H, 1);
    wconv_tiled<<<dim3(G4H / 64, P_ / 64), blk, 0, stream>>>(W1x, WT1x_, P_, G4H, 1);
    wconv_tiled<<<dim3(G4H / 64, H_ / 64), blk, 0, stream>>>(W1h, WT1h_, H_, G4H, 1);
    wconv_tiled<<<dim3(P_ / 64, H_ / 64), blk, 0, stream>>>(P0w, PT0w_, H_, P_, 0);
    wconv_tiled<<<dim3(P_ / 64, H_ / 64), blk, 0, stream>>>(P1w, PT1w_, H_, P_, 0);
    breorder_kernel<<<10, blk, 0, stream>>>(b0, b0r);
    breorder_kernel<<<10, blk, 0, stream>>>(b1, b1r);
    gather_kernel<<<(B_ * U_ * D_ / 4 + 255) / 256, blk, 0, stream>>>(tokens, embed, Xbf);

    // Recurrent layer driver: cooperative persistent kernel; on launch error,
    // print diagnostics and fall back to 512 per-step launches.
    auto run_lstm = [&](const __bf16* Zc, const __bf16* Wc) {
        zstate_kernel<<<160, blk, 0, stream>>>(hT0, hT1, hb0, hb1, cst);
        unsigned* t0 = hT0; unsigned* t1 = hT1; __bf16* Ha = Hbuf;
        const int* pl = plen;
        void* args[] = { (void*)&Zc, (void*)&Wc, (void*)&t0, (void*)&t1,
                         (void*)&Ha, (void*)&pl };
        hipError_t ce = hipLaunchCooperativeKernel((void*)lstm_seq_kernel,
                                                   dim3(NGRP * GWG), dim3(256),
                                                   args, 0, stream);
        if (ce != hipSuccess) {
            fprintf(stderr, "[lstm] coop launch failed: %d (%s) — per-step fallback\n",
                    (int)ce, hipGetErrorName(ce));
            for (int t = 0; t < U_; ++t) {
                const __bf16* hi = (t & 1) ? hb1 : hb0;
                __bf16*       ho = (t & 1) ? hb0 : hb1;
                lstm_step_fb<<<NWG, blk, 0, stream>>>(Zc, Wc, hi, ho, cst, Hbuf, plen, t);
            }
        }
    };

    // ---- layer 0 ----
    gemm_kernel<<<dim3(G4H / 64, B_ * U_ / 256), blk, 0, stream>>>(
        Xbf, WT0x_, b0r, nullptr, Z, B_ * U_, G4H, D_, 1);
    run_lstm(Z, WT0h_);
    ln_kernel<<<B_ * U_, blk, 0, stream>>>(Hbuf, g0, be0);
    gemm_kernel<<<dim3(P_ / 64, B_ * U_ / 256), blk, 0, stream>>>(
        Hbuf, PT0w_, P0b, nullptr, Xbf, B_ * U_, P_, H_, 0);

    // ---- layer 1 ----
    gemm_kernel<<<dim3(G4H / 64, B_ * U_ / 256), blk, 0, stream>>>(
        Xbf, WT1x_, b1r, nullptr, Z, B_ * U_, G4H, P_, 1);
    run_lstm(Z, WT1h_);
    ln_kernel<<<B_ * U_, blk, 0, stream>>>(Hbuf, g1, be1);
    gemm_kernel<<<dim3(P_ / 64, B_ * U_ / 256), blk, 0, stream>>>(
        Hbuf, PT1w_, P1b, out, nullptr, B_ * U_, P_, H_, 0);
}

// Round 20
// 4440.368 us; speedup vs baseline: 1.3683x; 1.3621x over previous
//
#include <hip/hip_runtime.h>
#include <hip/hip_bf16.h>
#include <cstdint>
#include <cstdio>

// Problem constants
#define B_   64
#define U_   512
#define D_   512
#define H_   640
#define P_   512
#define G4H  2560   // 4*H
#define NWG  40     // WGs in fallback recurrent path
#define NGRP 4      // independent batch groups (16 batches each)
#define GWG  40     // WGs per group (each owns 64 reordered gate cols)
#define HLP  648    // LDS h row stride (bf16): 1296 B rows -> 16B-aligned, 2-way banks (free)

typedef __bf16 bf16x8 __attribute__((ext_vector_type(8)));
typedef __bf16 bf16x4 __attribute__((ext_vector_type(4)));
typedef float  f32x4  __attribute__((ext_vector_type(4)));
typedef int    i32x4  __attribute__((ext_vector_type(4)));
typedef unsigned u32x2 __attribute__((ext_vector_type(2)));

__device__ __forceinline__ float sigm(float x)     { return 1.f / (1.f + __expf(-x)); }
__device__ __forceinline__ float tanhfast(float x) { return 1.f - 2.f / (1.f + __expf(2.f * x)); }

// IC-direct (bypass L1 + per-XCD L2) ops — explicit sc0 sc1.
__device__ __forceinline__ void sysflag_store(unsigned* p, unsigned v) {
    asm volatile("global_store_dword %0, %1, off sc0 sc1" :: "v"(p), "v"(v) : "memory");
}
__device__ __forceinline__ i32x4 icload_b128(const void* p) {
    i32x4 r;
    asm volatile("global_load_dwordx4 %0, %1, off sc0 sc1"
                 : "=v"(r) : "v"(p) : "memory");
    return r;
}

// ---------------------------------------------------------------------------
// Tiled weight transpose: W[K][N] f32 -> WT[N'][K] bf16, 64x64 LDS tiles.
__global__ __launch_bounds__(256) void wconv_tiled(
    const float* __restrict__ W, __bf16* __restrict__ WT, int K, int N, int reorder) {
    __shared__ __bf16 tl[64 * 65];
    const int t  = threadIdx.x;
    const int n0 = blockIdx.x * 64, k0 = blockIdx.y * 64;
    const int cr = t & 63, rr4 = t >> 6;
    #pragma unroll
    for (int i = 0; i < 16; ++i) {
        int rl = i * 4 + rr4;
        tl[cr * 65 + rl] = (__bf16)W[(size_t)(k0 + rl) * N + n0 + cr];
    }
    __syncthreads();
    #pragma unroll
    for (int i = 0; i < 16; ++i) {
        int nl = i * 4 + rr4;
        int n  = n0 + nl;
        int np = reorder ? (4 * (n % 640) + (n / 640)) : n;
        WT[(size_t)np * K + k0 + cr] = tl[nl * 65 + cr];
    }
}

__global__ __launch_bounds__(256) void breorder_kernel(
    const float* __restrict__ b, float* __restrict__ br) {
    int n = blockIdx.x * 256 + threadIdx.x;
    if (n < G4H) br[4 * (n % 640) + (n / 640)] = b[n];
}

__global__ __launch_bounds__(256) void gather_kernel(
    const int* __restrict__ tokens, const float* __restrict__ embed,
    __bf16* __restrict__ X) {
    int tid = blockIdx.x * 256 + threadIdx.x;
    int row = tid >> 7;
    int c4  = (tid & 127) << 2;
    int tok = tokens[row];
    float4 v = *reinterpret_cast<const float4*>(embed + (size_t)tok * D_ + c4);
    union { ushort4 u; __bf16 h[4]; } o;
    o.h[0] = (__bf16)v.x; o.h[1] = (__bf16)v.y; o.h[2] = (__bf16)v.z; o.h[3] = (__bf16)v.w;
    *reinterpret_cast<ushort4*>(X + (size_t)row * D_ + c4) = o.u;
}

// Zero tagged h buffers (fast path), dense h + c (fallback). 160 x 256 threads.
__global__ __launch_bounds__(256) void zstate_kernel(
    unsigned* __restrict__ hT0, unsigned* __restrict__ hT1,
    __bf16* __restrict__ h0, __bf16* __restrict__ h1,
    float* __restrict__ cst) {
    int tid = blockIdx.x * 256 + threadIdx.x;
    if (tid < B_ * H_) {                 // 40960 dwords each
        sysflag_store(&hT0[tid], 0u);    // tag 0, h = +0.0bf16
        sysflag_store(&hT1[tid], 0u);
        h0[tid] = (__bf16)0.f; h1[tid] = (__bf16)0.f; cst[tid] = 0.f;
    }
}

// ---------------------------------------------------------------------------
// bf16 MFMA GEMM: C[M][N] = A[M][K] @ BT[N][K]^T + bias[N]. WG tile 256x64
// (4 m-subtiles/wave -> B fragments reused 4x in registers).
// ztr=1 writes rows transposed (b*U+u -> u*B+b), for Z.
__global__ __launch_bounds__(256) void gemm_kernel(
    const __bf16* __restrict__ A, const __bf16* __restrict__ BT,
    const float* __restrict__ bias,
    float* __restrict__ Cf, __bf16* __restrict__ Cb,
    int M, int N, int K, int ztr) {
    const int wv = threadIdx.x >> 6, l = threadIdx.x & 63;
    const int lr = l & 15, lh = l >> 4;
    const int m0 = blockIdx.y * 256 + wv * 16;
    const int n0 = blockIdx.x * 64;

    f32x4 acc[4][4];
    #pragma unroll
    for (int mt = 0; mt < 4; ++mt)
        #pragma unroll
        for (int nt = 0; nt < 4; ++nt) acc[mt][nt] = (f32x4){0.f, 0.f, 0.f, 0.f};

    const __bf16* Ap[4];
    #pragma unroll
    for (int mt = 0; mt < 4; ++mt)
        Ap[mt] = A + (size_t)(m0 + mt * 64 + lr) * K + lh * 8;
    const __bf16* Bp = BT + (size_t)(n0 + lr) * K + lh * 8;

    for (int k0 = 0; k0 < K; k0 += 32) {
        bf16x8 af[4];
        #pragma unroll
        for (int mt = 0; mt < 4; ++mt)
            af[mt] = *reinterpret_cast<const bf16x8*>(Ap[mt] + k0);
        #pragma unroll
        for (int nt = 0; nt < 4; ++nt) {
            bf16x8 bfv = *reinterpret_cast<const bf16x8*>(Bp + (size_t)nt * 16 * K + k0);
            #pragma unroll
            for (int mt = 0; mt < 4; ++mt)
                acc[mt][nt] = __builtin_amdgcn_mfma_f32_16x16x32_bf16(af[mt], bfv, acc[mt][nt], 0, 0, 0);
        }
    }
    #pragma unroll
    for (int mt = 0; mt < 4; ++mt) {
        #pragma unroll
        for (int nt = 0; nt < 4; ++nt) {
            int col = n0 + nt * 16 + lr;
            float bs = bias ? bias[col] : 0.f;
            #pragma unroll
            for (int r = 0; r < 4; ++r) {
                int row = m0 + mt * 64 + lh * 4 + r;
                int crow = ztr ? ((row & (U_ - 1)) * B_ + (row >> 9)) : row;
                float v = acc[mt][nt][r] + bs;
                if (Cf) Cf[(size_t)crow * N + col] = v;
                else    Cb[(size_t)crow * N + col] = (__bf16)v;
            }
        }
    }
}

// ---------------------------------------------------------------------------
// Persistent LSTM kernel (cooperative, 160 WGs) — BYTE-IDENTICAL to R17's
// (measured best: 1.76 ms warm). Batch-grouped + TAGGED h exchange
// ((tag<<16)|bf16 dwords, sc0 sc1): no barrier, no flags, no store drain.
// HLP=648: 1296 B rows stay 16B-aligned (b128 LDS ops intact); the 650
// variant (R18/R19) silently split ds ops on odd rows and cost +45%.
__global__ __launch_bounds__(256, 1) void lstm_seq_kernel(
    const __bf16* __restrict__ Z,       // [U][B][G4H] bf16 (pre-transposed)
    const __bf16* __restrict__ WhT,     // [G4H][H_] reordered rows
    unsigned* hT0, unsigned* hT1,       // [B_][H_] tagged dwords ping-pong
    __bf16* __restrict__ Hout,          // [B_][U_][H_]
    const int* __restrict__ plen) {
    __shared__ __bf16 hl[16 * HLP];     // 20,736 B (tag-stripped h tile)
    __shared__ float  zl[16 * 65];      //  4,160 B
    __shared__ int    wflags[4];
    const int w = blockIdx.x, tid = threadIdx.x;
    const int g = w / GWG, wl = w % GWG;
    const int wv = tid >> 6, l = tid & 63;
    const int lr = l & 15, lh = l >> 4;

    // Wh slice -> registers (one-time, cached). 20 k-tiles of bf16x8 per lane.
    bf16x8 wreg[20];
    {
        const __bf16* Bp = WhT + (size_t)(wl * 64 + wv * 16 + lr) * H_ + lh * 8;
        #pragma unroll
        for (int kk = 0; kk < 20; ++kk)
            wreg[kk] = *reinterpret_cast<const bf16x8*>(Bp + kk * 32);
    }

    // Gate phase: thread owns (batch bb, hidden j = wl*16+jj)
    const int bb = tid >> 4, jj = tid & 15;
    const int bg = g * 16 + bb;
    const int pl = plen[bg];
    float c_r = 0.f, h_r = 0.f;

    for (unsigned t = 0; t < U_; ++t) {
        const unsigned* hTin = (t & 1u) ? hT1 : hT0;
        unsigned*      hTout = (t & 1u) ? hT0 : hT1;

        // ---- tag-poll load: retry until all 40 dwords/thread carry tag >= t
        i32x4 ld[10];
        int spin = 0;
        for (;;) {
            #pragma unroll
            for (int i = 0; i < 10; ++i) {
                int c = tid + i * 256;
                int row = c / 160, dcol = (c % 160) * 4;
                ld[i] = icload_b128(hTin + (size_t)(g * 16 + row) * H_ + dcol);
            }
            asm volatile("s_waitcnt vmcnt(0)" ::: "memory");
            __builtin_amdgcn_sched_barrier(0);
            bool ok = true;
            #pragma unroll
            for (int i = 0; i < 10; ++i)
                #pragma unroll
                for (int e = 0; e < 4; ++e)
                    ok &= (((unsigned)ld[i][e]) >> 16) >= t;
            bool wok = (__ballot(ok) == ~0ull);
            if (l == 0) wflags[wv] = wok ? 1 : 0;
            __syncthreads();   // also separates prior-step LDS reads from writes below
            bool all4 = wflags[0] && wflags[1] && wflags[2] && wflags[3];
            if (all4 || ++spin > 100000) break;
            __syncthreads();
        }

        // ---- strip tags -> LDS h tile
        #pragma unroll
        for (int i = 0; i < 10; ++i) {
            int c = tid + i * 256;
            int row = c / 160, dcol = (c % 160) * 4;
            u32x2 pk2;
            pk2[0] = ((unsigned)ld[i][0] & 0xFFFFu) | ((unsigned)ld[i][1] << 16);
            pk2[1] = ((unsigned)ld[i][2] & 0xFFFFu) | ((unsigned)ld[i][3] << 16);
            *reinterpret_cast<u32x2*>(hl + (size_t)row * HLP + dcol) = pk2;
        }
        // Z quad (cached) — issued here, consumed after sync; latency overlaps
        bf16x4 zq = *reinterpret_cast<const bf16x4*>(
            Z + ((size_t)t * B_ + bg) * G4H + wl * 64 + 4 * jj);
        __syncthreads();

        // ---- h @ Wh : A from LDS, B from registers
        f32x4 acc = (f32x4){0.f, 0.f, 0.f, 0.f};
        const __bf16* Al = hl + (size_t)lr * HLP + lh * 8;
        #pragma unroll
        for (int kk = 0; kk < 20; ++kk) {
            bf16x8 af = *reinterpret_cast<const bf16x8*>(Al + kk * 32);
            acc = __builtin_amdgcn_mfma_f32_16x16x32_bf16(af, wreg[kk], acc, 0, 0, 0);
        }
        // redistribute through LDS (MFMA layout -> gate layout)
        #pragma unroll
        for (int r = 0; r < 4; ++r)
            zl[(lh * 4 + r) * 65 + wv * 16 + lr] = acc[r];
        __syncthreads();

        // ---- gates + masked state update; tagged store (fire-and-forget)
        {
            const float* zp = &zl[bb * 65 + 4 * jj];
            float zi = zp[0] + (float)zq[0];
            float zf = zp[1] + (float)zq[1];
            float zg = zp[2] + (float)zq[2];
            float zo = zp[3] + (float)zq[3];
            float ig = sigm(zi), fg = sigm(zf), og = sigm(zo);
            float gg = tanhfast(zg);
            float cnew = fg * c_r + ig * gg;
            float hnew = og * tanhfast(cnew);
            bool m = (int)t < pl;
            c_r = m ? cnew : c_r;
            h_r = m ? hnew : h_r;
            union { __bf16 h; unsigned short u; } pk; pk.h = (__bf16)h_r;
            unsigned tag = ((t + 1u) << 16) | (unsigned)pk.u;
            sysflag_store(hTout + (size_t)bg * H_ + wl * 16 + jj, tag);
            Hout[((size_t)bg * U_ + t) * H_ + wl * 16 + jj] = pk.h;
        }
    }
}

// ---------------------------------------------------------------------------
// Fallback: one launch per timestep (inter-dispatch coherence). Dense h.
__global__ __launch_bounds__(256) void lstm_step_fb(
    const __bf16* __restrict__ Z, const __bf16* __restrict__ WhT,
    const __bf16* __restrict__ hin, __bf16* __restrict__ hout,
    float* __restrict__ cst, __bf16* __restrict__ Hout,
    const int* __restrict__ plen, int t) {
    __shared__ float zl[64 * 65];
    const int w = blockIdx.x, tid = threadIdx.x;
    const int wv = tid >> 6, l = tid & 63;
    const int lr = l & 15, lh = l >> 4;

    f32x4 acc[4];
    #pragma unroll
    for (int mt = 0; mt < 4; ++mt) acc[mt] = (f32x4){0.f, 0.f, 0.f, 0.f};
    const __bf16* Bp = WhT + (size_t)(w * 64 + wv * 16 + lr) * H_ + lh * 8;
    const __bf16* Ap = hin + (size_t)lr * H_ + lh * 8;
    for (int kk = 0; kk < 20; ++kk) {
        bf16x8 bfv = *reinterpret_cast<const bf16x8*>(Bp + kk * 32);
        #pragma unroll
        for (int mt = 0; mt < 4; ++mt) {
            bf16x8 af = *reinterpret_cast<const bf16x8*>(Ap + (size_t)mt * 16 * H_ + kk * 32);
            acc[mt] = __builtin_amdgcn_mfma_f32_16x16x32_bf16(af, bfv, acc[mt], 0, 0, 0);
        }
    }
    {
        int cl = wv * 16 + lr;
        #pragma unroll
        for (int mt = 0; mt < 4; ++mt)
            #pragma unroll
            for (int r = 0; r < 4; ++r)
                zl[(mt * 16 + lh * 4 + r) * 65 + cl] = acc[mt][r];
    }
    __syncthreads();

    const int bb0 = tid >> 3, jp = tid & 7;
    #pragma unroll
    for (int it = 0; it < 2; ++it) {
        const int bb = (it ? bb0 + 32 : bb0);
        const int pl = plen[bb];
        const bf16x8 zq = *reinterpret_cast<const bf16x8*>(
            Z + ((size_t)t * B_ + bb) * G4H + w * 64 + 8 * jp);
        const float* zp = &zl[bb * 65 + 8 * jp];
        const size_t co = (size_t)w * 16 + 2 * jp;
        union { __bf16 h[2]; unsigned u; } ho_, hi_;
        hi_.u = *reinterpret_cast<const unsigned*>(hin + (size_t)bb * H_ + co);
        #pragma unroll
        for (int e = 0; e < 2; ++e) {
            size_t sidx = (size_t)bb * H_ + co + e;
            float zi = zp[4 * e + 0] + (float)zq[4 * e + 0];
            float zf = zp[4 * e + 1] + (float)zq[4 * e + 1];
            float zg = zp[4 * e + 2] + (float)zq[4 * e + 2];
            float zo = zp[4 * e + 3] + (float)zq[4 * e + 3];
            float ig = sigm(zi), fg = sigm(zf), og = sigm(zo);
            float gg = tanhfast(zg);
            float cold = cst[sidx];
            float cnew = fg * cold + ig * gg;
            float hnew = og * tanhfast(cnew);
            bool m = t < pl;
            cst[sidx] = m ? cnew : cold;
            ho_.h[e] = m ? (__bf16)hnew : hi_.h[e];
        }
        *reinterpret_cast<unsigned*>(hout + (size_t)bb * H_ + co) = ho_.u;
        *reinterpret_cast<unsigned*>(Hout + ((size_t)bb * U_ + t) * H_ + co) = ho_.u;
    }
}

// ---------------------------------------------------------------------------
__global__ __launch_bounds__(256) void ln_kernel(
    __bf16* __restrict__ X, const float* __restrict__ gamma, const float* __restrict__ beta) {
    __shared__ float s1[256];
    __shared__ float s2[256];
    const int tid = threadIdx.x;
    __bf16* xp = X + (size_t)blockIdx.x * H_;
    float xv[3] = {0.f, 0.f, 0.f};
    float a = 0.f, b = 0.f;
    #pragma unroll
    for (int i = 0; i < 3; ++i) {
        int j = tid + 256 * i;
        if (j < H_) { float v = (float)xp[j]; xv[i] = v; a += v; b += v * v; }
    }
    s1[tid] = a; s2[tid] = b;
    __syncthreads();
    for (int st = 128; st > 0; st >>= 1) {
        if (tid < st) { s1[tid] += s1[tid + st]; s2[tid] += s2[tid + st]; }
        __syncthreads();
    }
    float mean = s1[0] * (1.f / H_);
    float var  = s2[0] * (1.f / H_) - mean * mean;
    float inv  = rsqrtf(var + 0.001f);
    #pragma unroll
    for (int i = 0; i < 3; ++i) {
        int j = tid + 256 * i;
        if (j < H_) xp[j] = (__bf16)((xv[i] - mean) * inv * gamma[j] + beta[j]);
    }
}

// ---------------------------------------------------------------------------
extern "C" void kernel_launch(void* const* d_in, const int* in_sizes, int n_in,
                              void* d_out, int out_size, void* d_ws, size_t ws_size,
                              hipStream_t stream) {
    (void)in_sizes; (void)n_in; (void)out_size;
    const int*   tokens = (const int*)d_in[0];
    const int*   plen   = (const int*)d_in[1];
    const float* embed  = (const float*)d_in[2];
    const float* W0x = (const float*)d_in[3];
    const float* W0h = (const float*)d_in[4];
    const float* b0  = (const float*)d_in[5];
    const float* g0  = (const float*)d_in[6];
    const float* be0 = (const float*)d_in[7];
    const float* P0w = (const float*)d_in[8];
    const float* P0b = (const float*)d_in[9];
    const float* W1x = (const float*)d_in[10];
    const float* W1h = (const float*)d_in[11];
    const float* b1  = (const float*)d_in[12];
    const float* g1  = (const float*)d_in[13];
    const float* be1 = (const float*)d_in[14];
    const float* P1w = (const float*)d_in[15];
    const float* P1b = (const float*)d_in[16];
    float* out = (float*)d_out;

    char* p = (char*)d_ws;
    size_t used = 0;
    auto take = [&](size_t bytes) {
        char* r = p; size_t pad = (bytes + 255) & ~(size_t)255;
        p += pad; used += pad; return r;
    };
    __bf16* WT0x_ = (__bf16*)take((size_t)G4H * D_ * 2);
    __bf16* WT0h_ = (__bf16*)take((size_t)G4H * H_ * 2);
    __bf16* WT1x_ = (__bf16*)take((size_t)G4H * P_ * 2);
    __bf16* WT1h_ = (__bf16*)take((size_t)G4H * H_ * 2);
    __bf16* PT0w_ = (__bf16*)take((size_t)P_ * H_ * 2);
    __bf16* PT1w_ = (__bf16*)take((size_t)P_ * H_ * 2);
    float*  b0r   = (float*)take(G4H * 4);
    float*  b1r   = (float*)take(G4H * 4);
    unsigned* hT0 = (unsigned*)take((size_t)B_ * H_ * 4);   // tagged ping
    unsigned* hT1 = (unsigned*)take((size_t)B_ * H_ * 4);   // tagged pong
    __bf16* hb0   = (__bf16*)take((size_t)B_ * H_ * 2);     // fallback dense
    __bf16* hb1   = (__bf16*)take((size_t)B_ * H_ * 2);
    float*  cst   = (float*)take((size_t)B_ * H_ * 4);
    __bf16* Hbuf  = (__bf16*)take((size_t)B_ * U_ * H_ * 2);
    __bf16* Z     = (__bf16*)take((size_t)B_ * U_ * G4H * 2);  // [U][B][4H]

    if (used > ws_size) {
        fprintf(stderr, "kernel_launch: ws_size too small (%zu < %zu)\n",
                ws_size, used);
        return;
    }
    // Xbf aliases d_out (67 MB f32): dead before the final GEMM overwrites d_out.
    __bf16* Xbf = (__bf16*)d_out;

    dim3 blk(256);
    // Tiled weight transposes (all dims multiples of 64)
    wconv_tiled<<<dim3(G4H / 64, D_ / 64), blk, 0, stream>>>(W0x, WT0x_, D_, G4H, 1);
    wconv_tiled<<<dim3(G4H / 64, H_ / 64), blk, 0, stream>>>(W0h, WT0h_, H_, G4H, 1);
    wconv_tiled<<<dim3(G4H / 64, P_ / 64), blk, 0, stream>>>(W1x, WT1x_, P_, G4H, 1);
    wconv_tiled<<<dim3(G4H / 64, H_ / 64), blk, 0, stream>>>(W1h, WT1h_, H_, G4H, 1);
    wconv_tiled<<<dim3(P_ / 64, H_ / 64), blk, 0, stream>>>(P0w, PT0w_, H_, P_, 0);
    wconv_tiled<<<dim3(P_ / 64, H_ / 64), blk, 0, stream>>>(P1w, PT1w_, H_, P_, 0);
    breorder_kernel<<<10, blk, 0, stream>>>(b0, b0r);
    breorder_kernel<<<10, blk, 0, stream>>>(b1, b1r);
    gather_kernel<<<(B_ * U_ * D_ / 4 + 255) / 256, blk, 0, stream>>>(tokens, embed, Xbf);

    // Recurrent layer driver: cooperative persistent kernel; on launch error,
    // print diagnostics and fall back to 512 per-step launches.
    auto run_lstm = [&](const __bf16* Zc, const __bf16* Wc) {
        zstate_kernel<<<160, blk, 0, stream>>>(hT0, hT1, hb0, hb1, cst);
        unsigned* t0 = hT0; unsigned* t1 = hT1; __bf16* Ha = Hbuf;
        const int* pl = plen;
        void* args[] = { (void*)&Zc, (void*)&Wc, (void*)&t0, (void*)&t1,
                         (void*)&Ha, (void*)&pl };
        hipError_t ce = hipLaunchCooperativeKernel((void*)lstm_seq_kernel,
                                                   dim3(NGRP * GWG), dim3(256),
                                                   args, 0, stream);
        if (ce != hipSuccess) {
            fprintf(stderr, "[lstm] coop launch failed: %d (%s) — per-step fallback\n",
                    (int)ce, hipGetErrorName(ce));
            for (int t = 0; t < U_; ++t) {
                const __bf16* hi = (t & 1) ? hb1 : hb0;
                __bf16*       ho = (t & 1) ? hb0 : hb1;
                lstm_step_fb<<<NWG, blk, 0, stream>>>(Zc, Wc, hi, ho, cst, Hbuf, plen, t);
            }
        }
    };

    // ---- layer 0 ----
    gemm_kernel<<<dim3(G4H / 64, B_ * U_ / 256), blk, 0, stream>>>(
        Xbf, WT0x_, b0r, nullptr, Z, B_ * U_, G4H, D_, 1);
    run_lstm(Z, WT0h_);
    ln_kernel<<<B_ * U_, blk, 0, stream>>>(Hbuf, g0, be0);
    gemm_kernel<<<dim3(P_ / 64, B_ * U_ / 256), blk, 0, stream>>>(
        Hbuf, PT0w_, P0b, nullptr, Xbf, B_ * U_, P_, H_, 0);

    // ---- layer 1 ----
    gemm_kernel<<<dim3(G4H / 64, B_ * U_ / 256), blk, 0, stream>>>(
        Xbf, WT1x_, b1r, nullptr, Z, B_ * U_, G4H, P_, 1);
    run_lstm(Z, WT1h_);
    ln_kernel<<<B_ * U_, blk, 0, stream>>>(Hbuf, g1, be1);
    gemm_kernel<<<dim3(P_ / 64, B_ * U_ / 256), blk, 0, stream>>>(
        Hbuf, PT1w_, P1b, out, nullptr, B_ * U_, P_, H_, 0);
}